// Round 1
// baseline (475.251 us; speedup 1.0000x reference)
//
#include <hip/hip_runtime.h>
#include <cstdint>
#include <cstddef>

#define BATCH 2
#define SEQ 2048
#define DMODEL 1024
#define NHEAD 16
#define DHEAD 64
#define DFF 4096
#define MTOT (BATCH * SEQ) /* 4096 */

typedef __bf16 bf16x8 __attribute__((ext_vector_type(8)));
typedef __bf16 bf16x4 __attribute__((ext_vector_type(4)));
typedef float f32x4 __attribute__((ext_vector_type(4)));

// ---------------------------------------------------------------------------
// async global->LDS, 16B per lane. LDS dest must be the wave-uniform base;
// HW writes lane i at base + i*16 (guide §5 / m97 / m104).
// ---------------------------------------------------------------------------
__device__ __forceinline__ void gload_lds16(const void* g, void* l) {
  __builtin_amdgcn_global_load_lds(
      (__attribute__((address_space(1))) void*)(uintptr_t)g,
      (__attribute__((address_space(3))) void*)(uint32_t)(uintptr_t)l,
      16, 0, 0);
}

// ---------------------------------------------------------------------------
// fp32 [K,N] -> bf16 [N,K] transpose (weights -> B^T layout for MFMA B-frags)
// ---------------------------------------------------------------------------
__global__ __launch_bounds__(256) void k_transpose_to_bf16(
    const float* __restrict__ w, __bf16* __restrict__ wt, int K, int N) {
  __shared__ float t[32][33];
  const int n0 = blockIdx.x * 32, k0 = blockIdx.y * 32;
  const int tx = threadIdx.x & 31, ty = threadIdx.x >> 5;  // 32 x 8
#pragma unroll
  for (int i = ty; i < 32; i += 8) t[i][tx] = w[(size_t)(k0 + i) * N + n0 + tx];
  __syncthreads();
#pragma unroll
  for (int i = ty; i < 32; i += 8)
    wt[(size_t)(n0 + i) * K + k0 + tx] = (__bf16)t[tx][i];
}

// fp32 -> bf16 elementwise (x conversion), 4 elems/thread
__global__ __launch_bounds__(256) void k_cvt_bf16(
    const float* __restrict__ in, __bf16* __restrict__ out, int n) {
  const int i = (blockIdx.x * 256 + threadIdx.x) * 4;
  if (i >= n) return;
  const float4 v = *(const float4*)(in + i);
  bf16x4 r;
  r[0] = (__bf16)v.x; r[1] = (__bf16)v.y; r[2] = (__bf16)v.z; r[3] = (__bf16)v.w;
  *(bf16x4*)(out + i) = r;
}

// concat 3 x 1024 f32 biases -> [3072]
__global__ void k_concat3(const float* __restrict__ a, const float* __restrict__ b,
                          const float* __restrict__ c, float* __restrict__ o) {
  const int i = blockIdx.x * 256 + threadIdx.x;
  if (i >= 3072) return;
  o[i] = (i < 1024) ? a[i] : (i < 2048) ? b[i - 1024] : c[i - 2048];
}

// ---------------------------------------------------------------------------
// bf16 MFMA GEMM: C[M,N] = A[M,K] @ B[K,N] + bias, B given transposed [N,K].
// 128x128 tile, BK=32, 256 threads = 4 waves (2x2), each wave 64x64 via
// 4x4 frags of mfma_f32_16x16x32_bf16. global_load_lds width-16 staging.
// ---------------------------------------------------------------------------
template <bool RELU, typename OutT>
__global__ __launch_bounds__(256) void k_gemm(
    const __bf16* __restrict__ A, const __bf16* __restrict__ BT,
    const float* __restrict__ bias, OutT* __restrict__ C, int M, int N, int K) {
  __shared__ __bf16 sA[128 * 32];
  __shared__ __bf16 sB[128 * 32];
  const int tid = threadIdx.x;
  const int lane = tid & 63;
  const int wv = tid >> 6;
  const int wm = wv >> 1, wn = wv & 1;
  const int lrow = lane & 15;
  const int lko = (lane >> 4) * 8;
  const int m0 = blockIdx.y * 128, n0 = blockIdx.x * 128;

  f32x4 acc[4][4];
#pragma unroll
  for (int r = 0; r < 4; ++r)
#pragma unroll
    for (int c = 0; c < 4; ++c) acc[r][c] = f32x4{0.f, 0.f, 0.f, 0.f};

  const int seg_l = wv * 64 + lane;  // LDS written lane-linear per wave
  for (int k0 = 0; k0 < K; k0 += 32) {
#pragma unroll
    for (int r = 0; r < 2; ++r) {
      const int seg = r * 256 + seg_l;
      const int row = seg >> 2;            // 4 x 16B segs per 64B row
      const int ks = (seg & 3) * 8;        // element offset in k
      gload_lds16(A + (size_t)(m0 + row) * K + k0 + ks,
                  &sA[(size_t)(r * 256 + wv * 64) * 8]);
      gload_lds16(BT + (size_t)(n0 + row) * K + k0 + ks,
                  &sB[(size_t)(r * 256 + wv * 64) * 8]);
    }
    __syncthreads();
    bf16x8 af[4], bfr[4];
#pragma unroll
    for (int r = 0; r < 4; ++r)
      af[r] = *(const bf16x8*)&sA[(wm * 64 + r * 16 + lrow) * 32 + lko];
#pragma unroll
    for (int c = 0; c < 4; ++c)
      bfr[c] = *(const bf16x8*)&sB[(wn * 64 + c * 16 + lrow) * 32 + lko];
#pragma unroll
    for (int r = 0; r < 4; ++r)
#pragma unroll
      for (int c = 0; c < 4; ++c)
        acc[r][c] =
            __builtin_amdgcn_mfma_f32_16x16x32_bf16(af[r], bfr[c], acc[r][c], 0, 0, 0);
    __syncthreads();
  }

  // epilogue: C/D layout col = lane&15, row = (lane>>4)*4 + j  (m89-verified)
#pragma unroll
  for (int r = 0; r < 4; ++r) {
    const int row = m0 + wm * 64 + r * 16 + (lane >> 4) * 4;
#pragma unroll
    for (int c = 0; c < 4; ++c) {
      const int col = n0 + wn * 64 + c * 16 + lrow;
      const float bb = bias[col];
#pragma unroll
      for (int j = 0; j < 4; ++j) {
        float v = acc[r][c][j] + bb;
        if (RELU) v = fmaxf(v, 0.f);
        C[(size_t)(row + j) * N + col] = (OutT)v;
      }
    }
  }
}

// ---------------------------------------------------------------------------
// Flash attention: qkv packed [M, 3072] bf16 (Q | K | V sections of 1024).
// Grid (SEQ/64, NHEAD, BATCH), 256 thr = 4 waves, wave owns 16 q-rows.
// KBLK=32 keys/iter: K tile + transposed V tile staged in padded LDS,
// online softmax in-register, P restaged via per-wave LDS for PV MFMAs.
// ---------------------------------------------------------------------------
__global__ __launch_bounds__(256) void k_attn(
    const __bf16* __restrict__ qkv, const float* __restrict__ mask,
    __bf16* __restrict__ out) {
  const int qb = blockIdx.x, h = blockIdx.y, b = blockIdx.z;
  const int tid = threadIdx.x, lane = tid & 63, wv = tid >> 6;
  const int lrow = lane & 15, lko = (lane >> 4) * 8;

  __shared__ __bf16 sK[32][72];    // +8 pad: conflict-free b128 reads
  __shared__ __bf16 sVT[64][40];   // V transposed, +8 pad
  __shared__ __bf16 sP[4][16][40]; // per-wave P staging

  const size_t base = (size_t)b * SEQ * 3072;
  const __bf16* Qb = qkv + base + h * 64;
  const __bf16* Kb = qkv + base + 1024 + h * 64;
  const __bf16* Vb = qkv + base + 2048 + h * 64;
  const float* maskb = mask + (size_t)b * SEQ;

  const int q0 = qb * 64 + wv * 16;
  bf16x8 qf0 = *(const bf16x8*)&Qb[(size_t)(q0 + lrow) * 3072 + lko];
  bf16x8 qf1 = *(const bf16x8*)&Qb[(size_t)(q0 + lrow) * 3072 + 32 + lko];

  float m[4], l[4];
  f32x4 o[4];
#pragma unroll
  for (int j = 0; j < 4; ++j) { m[j] = -3e38f; l[j] = 0.f; }
#pragma unroll
  for (int d = 0; d < 4; ++d) o[d] = f32x4{0.f, 0.f, 0.f, 0.f};

  const int srow = tid >> 3;        // 0..31
  const int scol = (tid & 7) * 8;   // 0..56

  for (int k0 = 0; k0 < SEQ; k0 += 32) {
    __syncthreads();  // previous iter's LDS reads done
    bf16x8 kv = *(const bf16x8*)&Kb[(size_t)(k0 + srow) * 3072 + scol];
    *(bf16x8*)&sK[srow][scol] = kv;
    bf16x8 vv = *(const bf16x8*)&Vb[(size_t)(k0 + srow) * 3072 + scol];
#pragma unroll
    for (int i = 0; i < 8; ++i) sVT[scol + i][srow] = vv[i];
    __syncthreads();

    // QK^T: scores [16q x 32k] as two 16-col frags
    f32x4 sc0 = f32x4{0.f, 0.f, 0.f, 0.f}, sc1 = f32x4{0.f, 0.f, 0.f, 0.f};
    {
      bf16x8 ka = *(const bf16x8*)&sK[lrow][lko];
      bf16x8 kb2 = *(const bf16x8*)&sK[lrow][32 + lko];
      sc0 = __builtin_amdgcn_mfma_f32_16x16x32_bf16(qf0, ka, sc0, 0, 0, 0);
      sc0 = __builtin_amdgcn_mfma_f32_16x16x32_bf16(qf1, kb2, sc0, 0, 0, 0);
      bf16x8 kc = *(const bf16x8*)&sK[16 + lrow][lko];
      bf16x8 kd = *(const bf16x8*)&sK[16 + lrow][32 + lko];
      sc1 = __builtin_amdgcn_mfma_f32_16x16x32_bf16(qf0, kc, sc1, 0, 0, 0);
      sc1 = __builtin_amdgcn_mfma_f32_16x16x32_bf16(qf1, kd, sc1, 0, 0, 0);
    }

    const float mk0 = maskb[k0 + lrow];
    const float mk1 = maskb[k0 + 16 + lrow];
    float pm[4], so[4], rs[4];
#pragma unroll
    for (int j = 0; j < 4; ++j) {
      sc0[j] = sc0[j] * 0.125f + mk0;
      sc1[j] = sc1[j] * 0.125f + mk1;
      pm[j] = fmaxf(sc0[j], sc1[j]);
    }
#pragma unroll
    for (int j = 0; j < 4; ++j)
#pragma unroll
      for (int off = 1; off < 16; off <<= 1)
        pm[j] = fmaxf(pm[j], __shfl_xor(pm[j], off));
#pragma unroll
    for (int j = 0; j < 4; ++j) {
      const float mn = fmaxf(m[j], pm[j]);
      so[j] = __expf(m[j] - mn);
      m[j] = mn;
      sc0[j] = __expf(sc0[j] - mn);
      sc1[j] = __expf(sc1[j] - mn);
      rs[j] = sc0[j] + sc1[j];
    }
#pragma unroll
    for (int j = 0; j < 4; ++j)
#pragma unroll
      for (int off = 1; off < 16; off <<= 1) rs[j] += __shfl_xor(rs[j], off);
#pragma unroll
    for (int j = 0; j < 4; ++j) l[j] = l[j] * so[j] + rs[j];
#pragma unroll
    for (int d = 0; d < 4; ++d)
#pragma unroll
      for (int j = 0; j < 4; ++j) o[d][j] *= so[j];

    // stage P (bf16) for PV A-frags (wave-internal; compiler orders LDS deps)
    const int prow = (lane >> 4) * 4;
#pragma unroll
    for (int j = 0; j < 4; ++j) {
      sP[wv][prow + j][lrow] = (__bf16)sc0[j];
      sP[wv][prow + j][16 + lrow] = (__bf16)sc1[j];
    }
    bf16x8 pa = *(const bf16x8*)&sP[wv][lrow][lko];
#pragma unroll
    for (int d = 0; d < 4; ++d) {
      bf16x8 vb2 = *(const bf16x8*)&sVT[d * 16 + lrow][lko];
      o[d] = __builtin_amdgcn_mfma_f32_16x16x32_bf16(pa, vb2, o[d], 0, 0, 0);
    }
  }

  const int prow = (lane >> 4) * 4;
  float inv[4];
#pragma unroll
  for (int j = 0; j < 4; ++j) inv[j] = 1.0f / l[j];
#pragma unroll
  for (int d = 0; d < 4; ++d)
#pragma unroll
    for (int j = 0; j < 4; ++j)
      out[((size_t)b * SEQ + q0 + prow + j) * DMODEL + h * 64 + d * 16 + lrow] =
          (__bf16)(o[d][j] * inv[j]);
}

// ---------------------------------------------------------------------------
// out = LayerNorm(x + y) * g + beta ; writes fp32 (residual) and opt bf16
// one row (1024) per block, 256 threads x 4 elems
// ---------------------------------------------------------------------------
__global__ __launch_bounds__(256) void k_add_ln(
    const float* __restrict__ x, const float* __restrict__ y,
    const float* __restrict__ g, const float* __restrict__ be,
    float* __restrict__ of, __bf16* __restrict__ ob) {
  const int row = blockIdx.x, tid = threadIdx.x;
  const float4 a = ((const float4*)(x + (size_t)row * 1024))[tid];
  const float4 b = ((const float4*)(y + (size_t)row * 1024))[tid];
  const float v0 = a.x + b.x, v1 = a.y + b.y, v2 = a.z + b.z, v3 = a.w + b.w;
  float s = v0 + v1 + v2 + v3;
  float s2 = v0 * v0 + v1 * v1 + v2 * v2 + v3 * v3;
#pragma unroll
  for (int off = 32; off > 0; off >>= 1) {
    s += __shfl_xor(s, off);
    s2 += __shfl_xor(s2, off);
  }
  __shared__ float red[2][4];
  const int wv = tid >> 6, lane = tid & 63;
  if (lane == 0) { red[0][wv] = s; red[1][wv] = s2; }
  __syncthreads();
  s = red[0][0] + red[0][1] + red[0][2] + red[0][3];
  s2 = red[1][0] + red[1][1] + red[1][2] + red[1][3];
  const float mean = s * (1.0f / 1024.0f);
  const float var = s2 * (1.0f / 1024.0f) - mean * mean;
  const float rstd = rsqrtf(var + 1e-5f);
  const float4 gg = ((const float4*)g)[tid];
  const float4 bt = ((const float4*)be)[tid];
  float4 r;
  r.x = (v0 - mean) * rstd * gg.x + bt.x;
  r.y = (v1 - mean) * rstd * gg.y + bt.y;
  r.z = (v2 - mean) * rstd * gg.z + bt.z;
  r.w = (v3 - mean) * rstd * gg.w + bt.w;
  ((float4*)(of + (size_t)row * 1024))[tid] = r;
  if (ob) {
    bf16x4 rb;
    rb[0] = (__bf16)r.x; rb[1] = (__bf16)r.y; rb[2] = (__bf16)r.z; rb[3] = (__bf16)r.w;
    *(bf16x4*)(ob + (size_t)row * 1024 + tid * 4) = rb;
  }
}

// ---------------------------------------------------------------------------
extern "C" void kernel_launch(void* const* d_in, const int* in_sizes, int n_in,
                              void* d_out, int out_size, void* d_ws, size_t ws_size,
                              hipStream_t stream) {
  const float* x = (const float*)d_in[0];
  const float* src_mask = (const float*)d_in[1];
  const float* w_q = (const float*)d_in[2];
  const float* b_q = (const float*)d_in[3];
  const float* w_k = (const float*)d_in[4];
  const float* b_k = (const float*)d_in[5];
  const float* w_v = (const float*)d_in[6];
  const float* b_v = (const float*)d_in[7];
  const float* w_o = (const float*)d_in[8];
  const float* b_o = (const float*)d_in[9];
  const float* w_ff1 = (const float*)d_in[10];
  const float* b_ff1 = (const float*)d_in[11];
  const float* w_ff2 = (const float*)d_in[12];
  const float* b_ff2 = (const float*)d_in[13];
  const float* ln1_g = (const float*)d_in[14];
  const float* ln1_b = (const float*)d_in[15];
  const float* ln2_g = (const float*)d_in[16];
  const float* ln2_b = (const float*)d_in[17];

  char* ws = (char*)d_ws;
  // workspace layout (bytes); ff reuses qkv+attn (32MB), ff2 reuses proj (16MB)
  constexpr size_t O_WQKVT = 0;                               // 3072x1024 bf16
  constexpr size_t O_WOT = O_WQKVT + 3072ull * 1024 * 2;      // 1024x1024 bf16
  constexpr size_t O_WFF1T = O_WOT + 1024ull * 1024 * 2;      // 4096x1024 bf16
  constexpr size_t O_WFF2T = O_WFF1T + 4096ull * 1024 * 2;    // 1024x4096 bf16
  constexpr size_t O_BQKV = O_WFF2T + 4096ull * 1024 * 2;     // 3072 f32
  constexpr size_t O_XBF = O_BQKV + 3072ull * 4;              // 4096x1024 bf16
  constexpr size_t O_QKV = O_XBF + 4096ull * 1024 * 2;        // 4096x3072 bf16
  constexpr size_t O_ATTN = O_QKV + 4096ull * 3072 * 2;       // 4096x1024 bf16
  constexpr size_t O_PROJ = O_ATTN + 4096ull * 1024 * 2;      // 4096x1024 f32
  constexpr size_t O_H1F = O_PROJ + 4096ull * 1024 * 4;       // 4096x1024 f32
  constexpr size_t O_H1B = O_H1F + 4096ull * 1024 * 4;        // 4096x1024 bf16
  constexpr size_t O_FF = O_QKV;    // 4096x4096 bf16 (reuse)
  constexpr size_t O_FF2 = O_PROJ;  // 4096x1024 f32 (reuse)

  __bf16* wqkvT = (__bf16*)(ws + O_WQKVT);
  __bf16* woT = (__bf16*)(ws + O_WOT);
  __bf16* wff1T = (__bf16*)(ws + O_WFF1T);
  __bf16* wff2T = (__bf16*)(ws + O_WFF2T);
  float* bqkv = (float*)(ws + O_BQKV);
  __bf16* xbf = (__bf16*)(ws + O_XBF);
  __bf16* qkvb = (__bf16*)(ws + O_QKV);
  __bf16* attnb = (__bf16*)(ws + O_ATTN);
  float* proj = (float*)(ws + O_PROJ);
  float* h1f = (float*)(ws + O_H1F);
  __bf16* h1b = (__bf16*)(ws + O_H1B);
  __bf16* ffb = (__bf16*)(ws + O_FF);
  float* ff2 = (float*)(ws + O_FF2);

  // weight prep
  k_transpose_to_bf16<<<dim3(32, 32), 256, 0, stream>>>(w_q, wqkvT, 1024, 1024);
  k_transpose_to_bf16<<<dim3(32, 32), 256, 0, stream>>>(w_k, wqkvT + 1024 * 1024, 1024, 1024);
  k_transpose_to_bf16<<<dim3(32, 32), 256, 0, stream>>>(w_v, wqkvT + 2 * 1024 * 1024, 1024, 1024);
  k_transpose_to_bf16<<<dim3(32, 32), 256, 0, stream>>>(w_o, woT, 1024, 1024);
  k_transpose_to_bf16<<<dim3(128, 32), 256, 0, stream>>>(w_ff1, wff1T, 1024, 4096);
  k_transpose_to_bf16<<<dim3(32, 128), 256, 0, stream>>>(w_ff2, wff2T, 4096, 1024);
  k_concat3<<<12, 256, 0, stream>>>(b_q, b_k, b_v, bqkv);
  k_cvt_bf16<<<4096, 256, 0, stream>>>(x, xbf, MTOT * DMODEL);

  // fused QKV projection: [4096,1024] x [1024,3072]
  k_gemm<false, __bf16><<<dim3(24, 32), 256, 0, stream>>>(xbf, wqkvT, bqkv, qkvb,
                                                          MTOT, 3072, 1024);
  // attention
  k_attn<<<dim3(SEQ / 64, NHEAD, BATCH), 256, 0, stream>>>(qkvb, src_mask, attnb);
  // output projection (f32 out)
  k_gemm<false, float><<<dim3(8, 32), 256, 0, stream>>>(attnb, woT, b_o, proj,
                                                        MTOT, 1024, 1024);
  // ln1: h1 = LN(x + proj)
  k_add_ln<<<4096, 256, 0, stream>>>(x, proj, ln1_g, ln1_b, h1f, h1b);
  // ff1 + relu: [4096,1024] x [1024,4096]
  k_gemm<true, __bf16><<<dim3(32, 32), 256, 0, stream>>>(h1b, wff1T, b_ff1, ffb,
                                                         MTOT, DFF, 1024);
  // ff2: [4096,4096] x [4096,1024]
  k_gemm<false, float><<<dim3(8, 32), 256, 0, stream>>>(ffb, wff2T, b_ff2, ff2,
                                                        MTOT, 1024, DFF);
  // ln2 -> d_out (fp32)
  k_add_ln<<<4096, 256, 0, stream>>>(h1f, ff2, ln2_g, ln2_b, (float*)d_out, nullptr);
}

// Round 2
// 291.321 us; speedup vs baseline: 1.6314x; 1.6314x over previous
//
#include <hip/hip_runtime.h>
#include <cstdint>
#include <cstddef>

#define BATCH 2
#define SEQ 2048
#define DMODEL 1024
#define NHEAD 16
#define DFF 4096
#define MTOT (BATCH * SEQ) /* 4096 */

typedef __bf16 bf16x8 __attribute__((ext_vector_type(8)));
typedef __bf16 bf16x4 __attribute__((ext_vector_type(4)));
typedef float f32x4 __attribute__((ext_vector_type(4)));

// async global->LDS, 16B/lane; LDS dest = wave-uniform base + lane*16 (m104).
__device__ __forceinline__ void gload_lds16(const void* g, void* l) {
  __builtin_amdgcn_global_load_lds(
      (__attribute__((address_space(1))) void*)(uintptr_t)g,
      (__attribute__((address_space(3))) void*)(uint32_t)(uintptr_t)l,
      16, 0, 0);
}

// ---------------------------------------------------------------------------
// fp32 [K,N] -> bf16 [N,K] transpose (weights -> B^T layout)
// ---------------------------------------------------------------------------
__global__ __launch_bounds__(256) void k_transpose_to_bf16(
    const float* __restrict__ w, __bf16* __restrict__ wt, int K, int N) {
  __shared__ float t[32][33];
  const int n0 = blockIdx.x * 32, k0 = blockIdx.y * 32;
  const int tx = threadIdx.x & 31, ty = threadIdx.x >> 5;
#pragma unroll
  for (int i = ty; i < 32; i += 8) t[i][tx] = w[(size_t)(k0 + i) * N + n0 + tx];
  __syncthreads();
#pragma unroll
  for (int i = ty; i < 32; i += 8)
    wt[(size_t)(n0 + i) * K + k0 + tx] = (__bf16)t[tx][i];
}

__global__ __launch_bounds__(256) void k_cvt_bf16(
    const float* __restrict__ in, __bf16* __restrict__ out, int n) {
  const int i = (blockIdx.x * 256 + threadIdx.x) * 4;
  if (i >= n) return;
  const float4 v = *(const float4*)(in + i);
  bf16x4 r;
  r[0] = (__bf16)v.x; r[1] = (__bf16)v.y; r[2] = (__bf16)v.z; r[3] = (__bf16)v.w;
  *(bf16x4*)(out + i) = r;
}

__global__ void k_concat3(const float* __restrict__ a, const float* __restrict__ b,
                          const float* __restrict__ c, float* __restrict__ o) {
  const int i = blockIdx.x * 256 + threadIdx.x;
  if (i >= 3072) return;
  o[i] = (i < 1024) ? a[i] : (i < 2048) ? b[i - 1024] : c[i - 2048];
}

// bf16 V-section transpose: qkvb[b*S+s][2048+c] -> vT[b*1024+c][s]
__global__ __launch_bounds__(256) void k_transpose_v(
    const __bf16* __restrict__ qkvb, __bf16* __restrict__ vT) {
  __shared__ __bf16 t[32][33];
  const int s0 = blockIdx.x * 32, c0 = blockIdx.y * 32, b = blockIdx.z;
  const int tx = threadIdx.x & 31, ty = threadIdx.x >> 5;
#pragma unroll
  for (int i = ty; i < 32; i += 8)
    t[i][tx] = qkvb[(size_t)(b * SEQ + s0 + i) * 3072 + 2048 + c0 + tx];
  __syncthreads();
#pragma unroll
  for (int i = ty; i < 32; i += 8)
    vT[((size_t)b * 1024 + c0 + i) * SEQ + s0 + tx] = t[tx][i];
}

// ---------------------------------------------------------------------------
// bf16 MFMA GEMM: C = A[M,K] @ B[K,N] + bias; B given transposed [N,K].
// BM = MF*32 (MF=4 -> 128, MF=2 -> 64), BN=128, BK=64, 4 waves (2x2).
// LDS rows 128B, XOR-swizzled via pre-swizzled global_load_lds source.
// ---------------------------------------------------------------------------
template <int MF, bool RELU, typename OutT>
__global__ __launch_bounds__(256) void k_gemm(
    const __bf16* __restrict__ A, const __bf16* __restrict__ BT,
    const float* __restrict__ bias, OutT* __restrict__ C, int M, int N, int K) {
  __shared__ __bf16 sA[MF * 32 * 64];
  __shared__ __bf16 sB[128 * 64];
  const int tid = threadIdx.x, lane = tid & 63, wv = tid >> 6;
  const int wm = wv >> 1, wn = wv & 1;
  const int lrow = lane & 15, hi = lane >> 4;
  const int m0 = blockIdx.y * (MF * 32), n0 = blockIdx.x * 128;
  const int srow = lane >> 3;
  const int scolE = ((lane & 7) ^ srow) * 8;  // pre-swizzled source col (elems)
  const int swz = (lrow & 7) << 4;            // read-side XOR (bytes)

  f32x4 acc[MF][4];
#pragma unroll
  for (int r = 0; r < MF; ++r)
#pragma unroll
    for (int c = 0; c < 4; ++c) acc[r][c] = f32x4{0.f, 0.f, 0.f, 0.f};

  for (int k0 = 0; k0 < K; k0 += 64) {
    __syncthreads();
#pragma unroll
    for (int rb = wv; rb < MF * 4; rb += 4) {
      const int row = rb * 8 + srow;
      gload_lds16(A + (size_t)(m0 + row) * K + k0 + scolE, &sA[rb * 512]);
    }
#pragma unroll
    for (int rb = wv; rb < 16; rb += 4) {
      const int row = rb * 8 + srow;
      gload_lds16(BT + (size_t)(n0 + row) * K + k0 + scolE, &sB[rb * 512]);
    }
    __syncthreads();
#pragma unroll
    for (int kc = 0; kc < 2; ++kc) {
      bf16x8 af[MF], bfr[4];
#pragma unroll
      for (int r = 0; r < MF; ++r) {
        const int row = wm * (MF * 16) + r * 16 + lrow;
        af[r] = *(const bf16x8*)((const char*)sA + row * 128 + ((kc * 64 + hi * 16) ^ swz));
      }
#pragma unroll
      for (int c = 0; c < 4; ++c) {
        const int row = wn * 64 + c * 16 + lrow;
        bfr[c] = *(const bf16x8*)((const char*)sB + row * 128 + ((kc * 64 + hi * 16) ^ swz));
      }
#pragma unroll
      for (int r = 0; r < MF; ++r)
#pragma unroll
        for (int c = 0; c < 4; ++c)
          acc[r][c] = __builtin_amdgcn_mfma_f32_16x16x32_bf16(af[r], bfr[c],
                                                              acc[r][c], 0, 0, 0);
    }
  }

#pragma unroll
  for (int r = 0; r < MF; ++r) {
    const int row = m0 + wm * (MF * 16) + r * 16 + hi * 4;
#pragma unroll
    for (int c = 0; c < 4; ++c) {
      const int col = n0 + wn * 64 + c * 16 + lrow;
      const float bb = bias[col];
#pragma unroll
      for (int j = 0; j < 4; ++j) {
        float v = acc[r][c][j] + bb;
        if (RELU) v = fmaxf(v, 0.f);
        C[(size_t)(row + j) * N + col] = (OutT)v;
      }
    }
  }
}

// ---------------------------------------------------------------------------
// Flash attention, swapped-operand QK^T (S^T = K*Q^T), in-register softmax.
// Grid (SEQ/64, NHEAD, BATCH), 4 waves x 16 q-rows, KVBLK=64.
// Lane (lrow=lane&15, hi=lane>>4): holds S[key=t*16+4hi+j][q=lrow] -> this IS
// the A-frag of v_mfma_f32_16x16x16_bf16 (k=(lane>>4)*4+j) => PV needs no
// cross-lane P movement. K and vT staged linearly with pre-swizzled source.
// ---------------------------------------------------------------------------
__global__ __launch_bounds__(256) void k_attn(
    const __bf16* __restrict__ qkv, const __bf16* __restrict__ vT,
    const float* __restrict__ mask, __bf16* __restrict__ out) {
  const int qb = blockIdx.x, h = blockIdx.y, b = blockIdx.z;
  const int tid = threadIdx.x, lane = tid & 63, wv = tid >> 6;
  const int lrow = lane & 15, hi = lane >> 4;

  __shared__ __bf16 sK[64 * 64];  // [key][d], swizzled
  __shared__ __bf16 sV[64 * 64];  // [d][key] (from vT), swizzled

  const size_t base = (size_t)b * SEQ * 3072;
  const __bf16* Qb = qkv + base + h * 64;
  const __bf16* Kb = qkv + base + 1024 + h * 64;
  const __bf16* vTb = vT + ((size_t)b * 1024 + h * 64) * SEQ;
  const float* maskb = mask + (size_t)b * SEQ;

  const int q0 = qb * 64 + wv * 16;
  // Q as B-operand: lane holds Q[q0+lrow][hi*8 + j (+32)]
  const bf16x8 qf0 = *(const bf16x8*)&Qb[(size_t)(q0 + lrow) * 3072 + hi * 8];
  const bf16x8 qf1 = *(const bf16x8*)&Qb[(size_t)(q0 + lrow) * 3072 + 32 + hi * 8];

  float m_r = -3e38f, l_r = 0.f;
  f32x4 o[4];
#pragma unroll
  for (int d = 0; d < 4; ++d) o[d] = f32x4{0.f, 0.f, 0.f, 0.f};

  const int srow = lane >> 3;
  const int scolE = ((lane & 7) ^ srow) * 8;
  const int swz = (lrow & 7) << 4;

  for (int k0 = 0; k0 < SEQ; k0 += 64) {
    __syncthreads();
#pragma unroll
    for (int r = 0; r < 2; ++r) {
      const int rb = r * 4 + wv;
      const int row = rb * 8 + srow;
      gload_lds16(Kb + (size_t)(k0 + row) * 3072 + scolE, &sK[rb * 512]);
      gload_lds16(vTb + (size_t)row * SEQ + k0 + scolE, &sV[rb * 512]);
    }
    __syncthreads();

    // S^T = K * Q^T : st[t][j] = S[key = t*16 + 4hi + j][q = lrow]
    f32x4 st[4];
#pragma unroll
    for (int t = 0; t < 4; ++t) {
      const int row = t * 16 + lrow;
      const char* rp = (const char*)sK + row * 128;
      const bf16x8 ka = *(const bf16x8*)(rp + ((hi * 16) ^ swz));
      const bf16x8 kb = *(const bf16x8*)(rp + ((64 + hi * 16) ^ swz));
      f32x4 a = f32x4{0.f, 0.f, 0.f, 0.f};
      a = __builtin_amdgcn_mfma_f32_16x16x32_bf16(ka, qf0, a, 0, 0, 0);
      a = __builtin_amdgcn_mfma_f32_16x16x32_bf16(kb, qf1, a, 0, 0, 0);
      st[t] = a;
    }

    float pm = -3e38f;
#pragma unroll
    for (int t = 0; t < 4; ++t) {
      const f32x4 mk = *(const f32x4*)&maskb[k0 + t * 16 + hi * 4];
#pragma unroll
      for (int j = 0; j < 4; ++j) {
        st[t][j] = st[t][j] * 0.125f + mk[j];
        pm = fmaxf(pm, st[t][j]);
      }
    }
    pm = fmaxf(pm, __shfl_xor(pm, 16));
    pm = fmaxf(pm, __shfl_xor(pm, 32));

    const float mn = fmaxf(m_r, pm);
    const float so = __expf(m_r - mn);
    m_r = mn;
    float rs = 0.f;
#pragma unroll
    for (int t = 0; t < 4; ++t)
#pragma unroll
      for (int j = 0; j < 4; ++j) {
        st[t][j] = __expf(st[t][j] - mn);
        rs += st[t][j];
      }
    rs += __shfl_xor(rs, 16);
    rs += __shfl_xor(rs, 32);
    l_r = l_r * so + rs;

    // o rows are q = 4hi+jj -> fetch so for those q's (held at lane lrow=q)
    float so_o[4];
#pragma unroll
    for (int jj = 0; jj < 4; ++jj) so_o[jj] = __shfl(so, hi * 4 + jj);
#pragma unroll
    for (int d = 0; d < 4; ++d)
#pragma unroll
      for (int jj = 0; jj < 4; ++jj) o[d][jj] *= so_o[jj];

    // P -> bf16 A-frags of 16x16x16 (already lane-correct: k = 4hi+j)
    bf16x4 pa[4];
#pragma unroll
    for (int t = 0; t < 4; ++t)
#pragma unroll
      for (int j = 0; j < 4; ++j) pa[t][j] = (__bf16)st[t][j];

    // O += P * V : B-frag = V[key=t*16+4hi+j][d0*16+lrow] from sV[d][key]
#pragma unroll
    for (int d = 0; d < 4; ++d) {
      const int row = d * 16 + lrow;
      const char* rp = (const char*)sV + row * 128;
#pragma unroll
      for (int t = 0; t < 4; ++t) {
        const bf16x4 vb = *(const bf16x4*)(rp + ((t * 32 + hi * 8) ^ swz));
        asm("v_mfma_f32_16x16x16_bf16 %0, %1, %2, %0"
            : "+v"(o[d])
            : "v"(pa[t]), "v"(vb));
      }
    }
  }

  __syncthreads();
  float linv[4];
#pragma unroll
  for (int jj = 0; jj < 4; ++jj) linv[jj] = 1.0f / __shfl(l_r, hi * 4 + jj);
#pragma unroll
  for (int d = 0; d < 4; ++d)
#pragma unroll
    for (int jj = 0; jj < 4; ++jj)
      out[((size_t)b * SEQ + q0 + hi * 4 + jj) * DMODEL + h * 64 + d * 16 + lrow] =
          (__bf16)(o[d][jj] * linv[jj]);
}

// ---------------------------------------------------------------------------
// out = LayerNorm(x + y) * g + beta ; writes fp32 residual and optional bf16
// ---------------------------------------------------------------------------
__global__ __launch_bounds__(256) void k_add_ln(
    const float* __restrict__ x, const float* __restrict__ y,
    const float* __restrict__ g, const float* __restrict__ be,
    float* __restrict__ of, __bf16* __restrict__ ob) {
  const int row = blockIdx.x, tid = threadIdx.x;
  const float4 a = ((const float4*)(x + (size_t)row * 1024))[tid];
  const float4 b = ((const float4*)(y + (size_t)row * 1024))[tid];
  const float v0 = a.x + b.x, v1 = a.y + b.y, v2 = a.z + b.z, v3 = a.w + b.w;
  float s = v0 + v1 + v2 + v3;
  float s2 = v0 * v0 + v1 * v1 + v2 * v2 + v3 * v3;
#pragma unroll
  for (int off = 32; off > 0; off >>= 1) {
    s += __shfl_xor(s, off);
    s2 += __shfl_xor(s2, off);
  }
  __shared__ float red[2][4];
  const int wv = tid >> 6, lane = tid & 63;
  if (lane == 0) { red[0][wv] = s; red[1][wv] = s2; }
  __syncthreads();
  s = red[0][0] + red[0][1] + red[0][2] + red[0][3];
  s2 = red[1][0] + red[1][1] + red[1][2] + red[1][3];
  const float mean = s * (1.0f / 1024.0f);
  const float var = s2 * (1.0f / 1024.0f) - mean * mean;
  const float rstd = rsqrtf(var + 1e-5f);
  const float4 gg = ((const float4*)g)[tid];
  const float4 bt = ((const float4*)be)[tid];
  float4 r;
  r.x = (v0 - mean) * rstd * gg.x + bt.x;
  r.y = (v1 - mean) * rstd * gg.y + bt.y;
  r.z = (v2 - mean) * rstd * gg.z + bt.z;
  r.w = (v3 - mean) * rstd * gg.w + bt.w;
  ((float4*)(of + (size_t)row * 1024))[tid] = r;
  if (ob) {
    bf16x4 rb;
    rb[0] = (__bf16)r.x; rb[1] = (__bf16)r.y; rb[2] = (__bf16)r.z; rb[3] = (__bf16)r.w;
    *(bf16x4*)(ob + (size_t)row * 1024 + tid * 4) = rb;
  }
}

// ---------------------------------------------------------------------------
extern "C" void kernel_launch(void* const* d_in, const int* in_sizes, int n_in,
                              void* d_out, int out_size, void* d_ws, size_t ws_size,
                              hipStream_t stream) {
  const float* x = (const float*)d_in[0];
  const float* src_mask = (const float*)d_in[1];
  const float* w_q = (const float*)d_in[2];
  const float* b_q = (const float*)d_in[3];
  const float* w_k = (const float*)d_in[4];
  const float* b_k = (const float*)d_in[5];
  const float* w_v = (const float*)d_in[6];
  const float* b_v = (const float*)d_in[7];
  const float* w_o = (const float*)d_in[8];
  const float* b_o = (const float*)d_in[9];
  const float* w_ff1 = (const float*)d_in[10];
  const float* b_ff1 = (const float*)d_in[11];
  const float* w_ff2 = (const float*)d_in[12];
  const float* b_ff2 = (const float*)d_in[13];
  const float* ln1_g = (const float*)d_in[14];
  const float* ln1_b = (const float*)d_in[15];
  const float* ln2_g = (const float*)d_in[16];
  const float* ln2_b = (const float*)d_in[17];

  char* ws = (char*)d_ws;
  constexpr size_t O_WQKVT = 0;                               // 3072x1024 bf16
  constexpr size_t O_WOT = O_WQKVT + 3072ull * 1024 * 2;      // 1024x1024 bf16
  constexpr size_t O_WFF1T = O_WOT + 1024ull * 1024 * 2;      // 4096x1024 bf16
  constexpr size_t O_WFF2T = O_WFF1T + 4096ull * 1024 * 2;    // 1024x4096 bf16
  constexpr size_t O_BQKV = O_WFF2T + 4096ull * 1024 * 2;     // 3072 f32
  constexpr size_t O_XBF = O_BQKV + 3072ull * 4;              // 4096x1024 bf16
  constexpr size_t O_QKV = O_XBF + 4096ull * 1024 * 2;        // 4096x3072 bf16
  constexpr size_t O_ATTN = O_QKV + 4096ull * 3072 * 2;       // 4096x1024 bf16
  constexpr size_t O_PROJ = O_ATTN + 4096ull * 1024 * 2;      // 4096x1024 f32
  constexpr size_t O_H1F = O_PROJ + 4096ull * 1024 * 4;       // 4096x1024 f32
  constexpr size_t O_H1B = O_H1F + 4096ull * 1024 * 4;        // 4096x1024 bf16
  constexpr size_t O_VT = O_PROJ;   // 2x1024x2048 bf16 (8MB, dead before proj)
  constexpr size_t O_FF = O_QKV;    // 4096x4096 bf16 (reuse)
  constexpr size_t O_FF2 = O_PROJ;  // 4096x1024 f32 (reuse, after ln1)

  __bf16* wqkvT = (__bf16*)(ws + O_WQKVT);
  __bf16* woT = (__bf16*)(ws + O_WOT);
  __bf16* wff1T = (__bf16*)(ws + O_WFF1T);
  __bf16* wff2T = (__bf16*)(ws + O_WFF2T);
  float* bqkv = (float*)(ws + O_BQKV);
  __bf16* xbf = (__bf16*)(ws + O_XBF);
  __bf16* qkvb = (__bf16*)(ws + O_QKV);
  __bf16* attnb = (__bf16*)(ws + O_ATTN);
  float* proj = (float*)(ws + O_PROJ);
  float* h1f = (float*)(ws + O_H1F);
  __bf16* h1b = (__bf16*)(ws + O_H1B);
  __bf16* vT = (__bf16*)(ws + O_VT);
  __bf16* ffb = (__bf16*)(ws + O_FF);
  float* ff2 = (float*)(ws + O_FF2);

  // weight prep
  k_transpose_to_bf16<<<dim3(32, 32), 256, 0, stream>>>(w_q, wqkvT, 1024, 1024);
  k_transpose_to_bf16<<<dim3(32, 32), 256, 0, stream>>>(w_k, wqkvT + 1024 * 1024, 1024, 1024);
  k_transpose_to_bf16<<<dim3(32, 32), 256, 0, stream>>>(w_v, wqkvT + 2 * 1024 * 1024, 1024, 1024);
  k_transpose_to_bf16<<<dim3(32, 32), 256, 0, stream>>>(w_o, woT, 1024, 1024);
  k_transpose_to_bf16<<<dim3(128, 32), 256, 0, stream>>>(w_ff1, wff1T, 1024, 4096);
  k_transpose_to_bf16<<<dim3(32, 128), 256, 0, stream>>>(w_ff2, wff2T, 4096, 1024);
  k_concat3<<<12, 256, 0, stream>>>(b_q, b_k, b_v, bqkv);
  k_cvt_bf16<<<4096, 256, 0, stream>>>(x, xbf, MTOT * DMODEL);

  // fused QKV projection
  k_gemm<4, false, __bf16><<<dim3(24, 32), 256, 0, stream>>>(xbf, wqkvT, bqkv, qkvb,
                                                             MTOT, 3072, 1024);
  // V transpose for attention B-frags
  k_transpose_v<<<dim3(64, 32, 2), 256, 0, stream>>>(qkvb, vT);
  // attention
  k_attn<<<dim3(SEQ / 64, NHEAD, BATCH), 256, 0, stream>>>(qkvb, vT, src_mask, attnb);
  // output projection (f32), BM=64 grid for 2 blocks/CU
  k_gemm<2, false, float><<<dim3(8, 64), 256, 0, stream>>>(attnb, woT, b_o, proj,
                                                           MTOT, 1024, 1024);
  // ln1
  k_add_ln<<<4096, 256, 0, stream>>>(x, proj, ln1_g, ln1_b, h1f, h1b);
  // ff1 + relu
  k_gemm<4, true, __bf16><<<dim3(32, 32), 256, 0, stream>>>(h1b, wff1T, b_ff1, ffb,
                                                            MTOT, DFF, 1024);
  // ff2
  k_gemm<2, false, float><<<dim3(8, 64), 256, 0, stream>>>(ffb, wff2T, b_ff2, ff2,
                                                           MTOT, 1024, DFF);
  // ln2 -> d_out
  k_add_ln<<<4096, 256, 0, stream>>>(h1f, ff2, ln2_g, ln2_b, (float*)d_out, nullptr);
}

// Round 9
// 284.999 us; speedup vs baseline: 1.6676x; 1.0222x over previous
//
#include <hip/hip_runtime.h>
#include <cstdint>
#include <cstddef>

#define BATCH 2
#define SEQ 2048
#define DMODEL 1024
#define NHEAD 16
#define DFF 4096
#define MTOT (BATCH * SEQ) /* 4096 */

typedef __bf16 bf16x8 __attribute__((ext_vector_type(8)));
typedef __bf16 bf16x4 __attribute__((ext_vector_type(4)));
typedef float f32x4 __attribute__((ext_vector_type(4)));

// async global->LDS, 16B/lane; LDS dest = wave-uniform base + lane*16 (m104).
__device__ __forceinline__ void gload_lds16(const void* g, void* l) {
  __builtin_amdgcn_global_load_lds(
      (__attribute__((address_space(1))) void*)(uintptr_t)g,
      (__attribute__((address_space(3))) void*)(uint32_t)(uintptr_t)l,
      16, 0, 0);
}

// ---------------------------------------------------------------------------
// fp32 [K,N] -> bf16 [N,K] transpose (weights -> B^T layout)
// ---------------------------------------------------------------------------
__global__ __launch_bounds__(256) void k_transpose_to_bf16(
    const float* __restrict__ w, __bf16* __restrict__ wt, int K, int N) {
  __shared__ float t[32][33];
  const int n0 = blockIdx.x * 32, k0 = blockIdx.y * 32;
  const int tx = threadIdx.x & 31, ty = threadIdx.x >> 5;
#pragma unroll
  for (int i = ty; i < 32; i += 8) t[i][tx] = w[(size_t)(k0 + i) * N + n0 + tx];
  __syncthreads();
#pragma unroll
  for (int i = ty; i < 32; i += 8)
    wt[(size_t)(n0 + i) * K + k0 + tx] = (__bf16)t[tx][i];
}

__global__ __launch_bounds__(256) void k_cvt_bf16(
    const float* __restrict__ in, __bf16* __restrict__ out, int n) {
  const int i = (blockIdx.x * 256 + threadIdx.x) * 4;
  if (i >= n) return;
  const float4 v = *(const float4*)(in + i);
  bf16x4 r;
  r[0] = (__bf16)v.x; r[1] = (__bf16)v.y; r[2] = (__bf16)v.z; r[3] = (__bf16)v.w;
  *(bf16x4*)(out + i) = r;
}

__global__ void k_concat3(const float* __restrict__ a, const float* __restrict__ b,
                          const float* __restrict__ c, float* __restrict__ o) {
  const int i = blockIdx.x * 256 + threadIdx.x;
  if (i >= 3072) return;
  o[i] = (i < 1024) ? a[i] : (i < 2048) ? b[i - 1024] : c[i - 2048];
}

// bf16 V-section transpose: qkvb[b*S+s][2048+c] -> vT[b*1024+c][s]
__global__ __launch_bounds__(256) void k_transpose_v(
    const __bf16* __restrict__ qkvb, __bf16* __restrict__ vT) {
  __shared__ __bf16 t[32][33];
  const int s0 = blockIdx.x * 32, c0 = blockIdx.y * 32, b = blockIdx.z;
  const int tx = threadIdx.x & 31, ty = threadIdx.x >> 5;
#pragma unroll
  for (int i = ty; i < 32; i += 8)
    t[i][tx] = qkvb[(size_t)(b * SEQ + s0 + i) * 3072 + 2048 + c0 + tx];
  __syncthreads();
#pragma unroll
  for (int i = ty; i < 32; i += 8)
    vT[((size_t)b * 1024 + c0 + i) * SEQ + s0 + tx] = t[tx][i];
}

// ---------------------------------------------------------------------------
// bf16 MFMA GEMM (round-2 verified body): BM=MF*32, BN=128, BK=64, 4 waves.
// ONLY delta vs round 2: T1 XCD-aware bijective block swizzle (requires
// nwg % 8 == 0; grids are 768/512/1024/512). Failure mode of a bad swizzle
// is wrong-tile placement (finite absmax), never NaN.
// ---------------------------------------------------------------------------
template <int MF, bool RELU, typename OutT>
__global__ __launch_bounds__(256) void k_gemm(
    const __bf16* __restrict__ A, const __bf16* __restrict__ BT,
    const float* __restrict__ bias, OutT* __restrict__ C, int M, int N, int K) {
  __shared__ __bf16 sA[MF * 32 * 64];
  __shared__ __bf16 sB[128 * 64];
  const int tid = threadIdx.x, lane = tid & 63, wv = tid >> 6;
  const int wm = wv >> 1, wn = wv & 1;
  const int lrow = lane & 15, hi = lane >> 4;
  const int nwg = gridDim.x * gridDim.y;
  const int flat = blockIdx.y * gridDim.x + blockIdx.x;
  const int cpx = nwg >> 3;
  const int swzb = (flat & 7) * cpx + (flat >> 3);
  const int m0 = (swzb / gridDim.x) * (MF * 32);
  const int n0 = (swzb % gridDim.x) * 128;
  const int srow = lane >> 3;
  const int scolE = ((lane & 7) ^ srow) * 8;
  const int swz = (lrow & 7) << 4;

  f32x4 acc[MF][4];
#pragma unroll
  for (int r = 0; r < MF; ++r)
#pragma unroll
    for (int c = 0; c < 4; ++c) acc[r][c] = f32x4{0.f, 0.f, 0.f, 0.f};

  for (int k0 = 0; k0 < K; k0 += 64) {
    __syncthreads();
#pragma unroll
    for (int rb = wv; rb < MF * 4; rb += 4) {
      const int row = rb * 8 + srow;
      gload_lds16(A + (size_t)(m0 + row) * K + k0 + scolE, &sA[rb * 512]);
    }
#pragma unroll
    for (int rb = wv; rb < 16; rb += 4) {
      const int row = rb * 8 + srow;
      gload_lds16(BT + (size_t)(n0 + row) * K + k0 + scolE, &sB[rb * 512]);
    }
    __syncthreads();
#pragma unroll
    for (int kc = 0; kc < 2; ++kc) {
      bf16x8 af[MF], bfr[4];
#pragma unroll
      for (int r = 0; r < MF; ++r) {
        const int row = wm * (MF * 16) + r * 16 + lrow;
        af[r] = *(const bf16x8*)((const char*)sA + row * 128 + ((kc * 64 + hi * 16) ^ swz));
      }
#pragma unroll
      for (int c = 0; c < 4; ++c) {
        const int row = wn * 64 + c * 16 + lrow;
        bfr[c] = *(const bf16x8*)((const char*)sB + row * 128 + ((kc * 64 + hi * 16) ^ swz));
      }
#pragma unroll
      for (int r = 0; r < MF; ++r)
#pragma unroll
        for (int c = 0; c < 4; ++c)
          acc[r][c] = __builtin_amdgcn_mfma_f32_16x16x32_bf16(af[r], bfr[c],
                                                              acc[r][c], 0, 0, 0);
    }
  }

#pragma unroll
  for (int r = 0; r < MF; ++r) {
    const int row = m0 + wm * (MF * 16) + r * 16 + hi * 4;
#pragma unroll
    for (int c = 0; c < 4; ++c) {
      const int col = n0 + wn * 64 + c * 16 + lrow;
      const float bb = bias[col];
#pragma unroll
      for (int j = 0; j < 4; ++j) {
        float v = acc[r][c][j] + bb;
        if (RELU) v = fmaxf(v, 0.f);
        C[(size_t)(row + j) * N + col] = (OutT)v;
      }
    }
  }
}

// ---------------------------------------------------------------------------
// Flash attention — EXACT round-2 body (single-buffer sync→gload→sync
// staging, __expf softmax, raw mask). No pipelining.
// ---------------------------------------------------------------------------
__global__ __launch_bounds__(256) void k_attn(
    const __bf16* __restrict__ qkv, const __bf16* __restrict__ vT,
    const float* __restrict__ mask, __bf16* __restrict__ out) {
  const int qb = blockIdx.x, h = blockIdx.y, b = blockIdx.z;
  const int tid = threadIdx.x, lane = tid & 63, wv = tid >> 6;
  const int lrow = lane & 15, hi = lane >> 4;

  __shared__ __bf16 sK[64 * 64];  // [key][d], swizzled
  __shared__ __bf16 sV[64 * 64];  // [d][key] (from vT), swizzled

  const size_t base = (size_t)b * SEQ * 3072;
  const __bf16* Qb = qkv + base + h * 64;
  const __bf16* Kb = qkv + base + 1024 + h * 64;
  const __bf16* vTb = vT + ((size_t)b * 1024 + h * 64) * SEQ;
  const float* maskb = mask + (size_t)b * SEQ;

  const int q0 = qb * 64 + wv * 16;
  const bf16x8 qf0 = *(const bf16x8*)&Qb[(size_t)(q0 + lrow) * 3072 + hi * 8];
  const bf16x8 qf1 = *(const bf16x8*)&Qb[(size_t)(q0 + lrow) * 3072 + 32 + hi * 8];

  float m_r = -3e38f, l_r = 0.f;
  f32x4 o[4];
#pragma unroll
  for (int d = 0; d < 4; ++d) o[d] = f32x4{0.f, 0.f, 0.f, 0.f};

  const int srow = lane >> 3;
  const int scolE = ((lane & 7) ^ srow) * 8;
  const int swz = (lrow & 7) << 4;

  for (int k0 = 0; k0 < SEQ; k0 += 64) {
    __syncthreads();
#pragma unroll
    for (int r = 0; r < 2; ++r) {
      const int rb = r * 4 + wv;
      const int row = rb * 8 + srow;
      gload_lds16(Kb + (size_t)(k0 + row) * 3072 + scolE, &sK[rb * 512]);
      gload_lds16(vTb + (size_t)row * SEQ + k0 + scolE, &sV[rb * 512]);
    }
    __syncthreads();

    // S^T = K * Q^T : st[t4][j] = S[key = t4*16 + 4hi + j][q = lrow]
    f32x4 st[4];
#pragma unroll
    for (int t4 = 0; t4 < 4; ++t4) {
      const char* rp = (const char*)sK + (t4 * 16 + lrow) * 128;
      const bf16x8 ka = *(const bf16x8*)(rp + ((hi * 16) ^ swz));
      const bf16x8 kb = *(const bf16x8*)(rp + ((64 + hi * 16) ^ swz));
      f32x4 a = f32x4{0.f, 0.f, 0.f, 0.f};
      a = __builtin_amdgcn_mfma_f32_16x16x32_bf16(ka, qf0, a, 0, 0, 0);
      a = __builtin_amdgcn_mfma_f32_16x16x32_bf16(kb, qf1, a, 0, 0, 0);
      st[t4] = a;
    }

    float pm = -3e38f;
#pragma unroll
    for (int t4 = 0; t4 < 4; ++t4) {
      const f32x4 mk = *(const f32x4*)&maskb[k0 + t4 * 16 + hi * 4];
#pragma unroll
      for (int j = 0; j < 4; ++j) {
        st[t4][j] = st[t4][j] * 0.125f + mk[j];
        pm = fmaxf(pm, st[t4][j]);
      }
    }
    pm = fmaxf(pm, __shfl_xor(pm, 16));
    pm = fmaxf(pm, __shfl_xor(pm, 32));

    const float mn = fmaxf(m_r, pm);
    const float so = __expf(m_r - mn);
    m_r = mn;
    float rs = 0.f;
#pragma unroll
    for (int t4 = 0; t4 < 4; ++t4)
#pragma unroll
      for (int j = 0; j < 4; ++j) {
        st[t4][j] = __expf(st[t4][j] - mn);
        rs += st[t4][j];
      }
    rs += __shfl_xor(rs, 16);
    rs += __shfl_xor(rs, 32);
    l_r = l_r * so + rs;

    float so_o[4];
#pragma unroll
    for (int jj = 0; jj < 4; ++jj) so_o[jj] = __shfl(so, hi * 4 + jj);
#pragma unroll
    for (int d = 0; d < 4; ++d)
#pragma unroll
      for (int jj = 0; jj < 4; ++jj) o[d][jj] *= so_o[jj];

    bf16x4 pa[4];
#pragma unroll
    for (int t4 = 0; t4 < 4; ++t4)
#pragma unroll
      for (int j = 0; j < 4; ++j) pa[t4][j] = (__bf16)st[t4][j];

#pragma unroll
    for (int d = 0; d < 4; ++d) {
      const char* rp = (const char*)sV + (d * 16 + lrow) * 128;
#pragma unroll
      for (int t4 = 0; t4 < 4; ++t4) {
        const bf16x4 vb = *(const bf16x4*)(rp + ((t4 * 32 + hi * 8) ^ swz));
        asm("v_mfma_f32_16x16x16_bf16 %0, %1, %2, %0"
            : "+v"(o[d])
            : "v"(pa[t4]), "v"(vb));
      }
    }
  }

  __syncthreads();
  float linv[4];
#pragma unroll
  for (int jj = 0; jj < 4; ++jj) linv[jj] = 1.0f / __shfl(l_r, hi * 4 + jj);
#pragma unroll
  for (int d = 0; d < 4; ++d)
#pragma unroll
    for (int jj = 0; jj < 4; ++jj)
      out[((size_t)b * SEQ + q0 + hi * 4 + jj) * DMODEL + h * 64 + d * 16 + lrow] =
          (__bf16)(o[d][jj] * linv[jj]);
}

// ---------------------------------------------------------------------------
// out = LayerNorm(x + y) * g + beta ; writes fp32 residual and optional bf16
// ---------------------------------------------------------------------------
__global__ __launch_bounds__(256) void k_add_ln(
    const float* __restrict__ x, const float* __restrict__ y,
    const float* __restrict__ g, const float* __restrict__ be,
    float* __restrict__ of, __bf16* __restrict__ ob) {
  const int row = blockIdx.x, tid = threadIdx.x;
  const float4 a = ((const float4*)(x + (size_t)row * 1024))[tid];
  const float4 b = ((const float4*)(y + (size_t)row * 1024))[tid];
  const float v0 = a.x + b.x, v1 = a.y + b.y, v2 = a.z + b.z, v3 = a.w + b.w;
  float s = v0 + v1 + v2 + v3;
  float s2 = v0 * v0 + v1 * v1 + v2 * v2 + v3 * v3;
#pragma unroll
  for (int off = 32; off > 0; off >>= 1) {
    s += __shfl_xor(s, off);
    s2 += __shfl_xor(s2, off);
  }
  __shared__ float red[2][4];
  const int wv = tid >> 6, lane = tid & 63;
  if (lane == 0) { red[0][wv] = s; red[1][wv] = s2; }
  __syncthreads();
  s = red[0][0] + red[0][1] + red[0][2] + red[0][3];
  s2 = red[1][0] + red[1][1] + red[1][2] + red[1][3];
  const float mean = s * (1.0f / 1024.0f);
  const float var = s2 * (1.0f / 1024.0f) - mean * mean;
  const float rstd = rsqrtf(var + 1e-5f);
  const float4 gg = ((const float4*)g)[tid];
  const float4 bt = ((const float4*)be)[tid];
  float4 r;
  r.x = (v0 - mean) * rstd * gg.x + bt.x;
  r.y = (v1 - mean) * rstd * gg.y + bt.y;
  r.z = (v2 - mean) * rstd * gg.z + bt.z;
  r.w = (v3 - mean) * rstd * gg.w + bt.w;
  ((float4*)(of + (size_t)row * 1024))[tid] = r;
  if (ob) {
    bf16x4 rb;
    rb[0] = (__bf16)r.x; rb[1] = (__bf16)r.y; rb[2] = (__bf16)r.z; rb[3] = (__bf16)r.w;
    *(bf16x4*)(ob + (size_t)row * 1024 + tid * 4) = rb;
  }
}

// ---------------------------------------------------------------------------
extern "C" void kernel_launch(void* const* d_in, const int* in_sizes, int n_in,
                              void* d_out, int out_size, void* d_ws, size_t ws_size,
                              hipStream_t stream) {
  const float* x = (const float*)d_in[0];
  const float* src_mask = (const float*)d_in[1];
  const float* w_q = (const float*)d_in[2];
  const float* b_q = (const float*)d_in[3];
  const float* w_k = (const float*)d_in[4];
  const float* b_k = (const float*)d_in[5];
  const float* w_v = (const float*)d_in[6];
  const float* b_v = (const float*)d_in[7];
  const float* w_o = (const float*)d_in[8];
  const float* b_o = (const float*)d_in[9];
  const float* w_ff1 = (const float*)d_in[10];
  const float* b_ff1 = (const float*)d_in[11];
  const float* w_ff2 = (const float*)d_in[12];
  const float* b_ff2 = (const float*)d_in[13];
  const float* ln1_g = (const float*)d_in[14];
  const float* ln1_b = (const float*)d_in[15];
  const float* ln2_g = (const float*)d_in[16];
  const float* ln2_b = (const float*)d_in[17];

  char* ws = (char*)d_ws;
  constexpr size_t O_WQKVT = 0;                               // 3072x1024 bf16
  constexpr size_t O_WOT = O_WQKVT + 3072ull * 1024 * 2;      // 1024x1024 bf16
  constexpr size_t O_WFF1T = O_WOT + 1024ull * 1024 * 2;      // 4096x1024 bf16
  constexpr size_t O_WFF2T = O_WFF1T + 4096ull * 1024 * 2;    // 1024x4096 bf16
  constexpr size_t O_BQKV = O_WFF2T + 4096ull * 1024 * 2;     // 3072 f32
  constexpr size_t O_XBF = O_BQKV + 3072ull * 4;              // 4096x1024 bf16
  constexpr size_t O_QKV = O_XBF + 4096ull * 1024 * 2;        // 4096x3072 bf16
  constexpr size_t O_ATTN = O_QKV + 4096ull * 3072 * 2;       // 4096x1024 bf16
  constexpr size_t O_PROJ = O_ATTN + 4096ull * 1024 * 2;      // 4096x1024 f32
  constexpr size_t O_H1F = O_PROJ + 4096ull * 1024 * 4;       // 4096x1024 f32
  constexpr size_t O_H1B = O_H1F + 4096ull * 1024 * 4;        // 4096x1024 bf16
  constexpr size_t O_VT = O_PROJ;   // 2x1024x2048 bf16 (dead before proj)
  constexpr size_t O_FF = O_QKV;    // 4096x4096 bf16 (reuse)
  constexpr size_t O_FF2 = O_PROJ;  // 4096x1024 f32 (reuse, after ln1)

  __bf16* wqkvT = (__bf16*)(ws + O_WQKVT);
  __bf16* woT = (__bf16*)(ws + O_WOT);
  __bf16* wff1T = (__bf16*)(ws + O_WFF1T);
  __bf16* wff2T = (__bf16*)(ws + O_WFF2T);
  float* bqkv = (float*)(ws + O_BQKV);
  __bf16* xbf = (__bf16*)(ws + O_XBF);
  __bf16* qkvb = (__bf16*)(ws + O_QKV);
  __bf16* attnb = (__bf16*)(ws + O_ATTN);
  float* proj = (float*)(ws + O_PROJ);
  float* h1f = (float*)(ws + O_H1F);
  __bf16* h1b = (__bf16*)(ws + O_H1B);
  __bf16* vT = (__bf16*)(ws + O_VT);
  __bf16* ffb = (__bf16*)(ws + O_FF);
  float* ff2 = (float*)(ws + O_FF2);

  // weight prep
  k_transpose_to_bf16<<<dim3(32, 32), 256, 0, stream>>>(w_q, wqkvT, 1024, 1024);
  k_transpose_to_bf16<<<dim3(32, 32), 256, 0, stream>>>(w_k, wqkvT + 1024 * 1024, 1024, 1024);
  k_transpose_to_bf16<<<dim3(32, 32), 256, 0, stream>>>(w_v, wqkvT + 2 * 1024 * 1024, 1024, 1024);
  k_transpose_to_bf16<<<dim3(32, 32), 256, 0, stream>>>(w_o, woT, 1024, 1024);
  k_transpose_to_bf16<<<dim3(128, 32), 256, 0, stream>>>(w_ff1, wff1T, 1024, 4096);
  k_transpose_to_bf16<<<dim3(32, 128), 256, 0, stream>>>(w_ff2, wff2T, 4096, 1024);
  k_concat3<<<12, 256, 0, stream>>>(b_q, b_k, b_v, bqkv);
  k_cvt_bf16<<<4096, 256, 0, stream>>>(x, xbf, MTOT * DMODEL);

  // fused QKV projection
  k_gemm<4, false, __bf16><<<dim3(24, 32), 256, 0, stream>>>(xbf, wqkvT, bqkv, qkvb,
                                                             MTOT, 3072, 1024);
  // V transpose for attention B-frags
  k_transpose_v<<<dim3(64, 32, 2), 256, 0, stream>>>(qkvb, vT);
  // attention (round-2 exact)
  k_attn<<<dim3(SEQ / 64, NHEAD, BATCH), 256, 0, stream>>>(qkvb, vT, src_mask, attnb);
  // output projection (f32)
  k_gemm<2, false, float><<<dim3(8, 64), 256, 0, stream>>>(attnb, woT, b_o, proj,
                                                           MTOT, 1024, 1024);
  // ln1
  k_add_ln<<<4096, 256, 0, stream>>>(x, proj, ln1_g, ln1_b, h1f, h1b);
  // ff1 + relu
  k_gemm<4, true, __bf16><<<dim3(32, 32), 256, 0, stream>>>(h1b, wff1T, b_ff1, ffb,
                                                            MTOT, DFF, 1024);
  // ff2
  k_gemm<2, false, float><<<dim3(8, 64), 256, 0, stream>>>(ffb, wff2T, b_ff2, ff2,
                                                           MTOT, 1024, DFF);
  // ln2 -> d_out
  k_add_ln<<<4096, 256, 0, stream>>>(h1f, ff2, ln2_g, ln2_b, (float*)d_out, nullptr);
}